// Round 1
// baseline (1413.282 us; speedup 1.0000x reference)
//
#include <hip/hip_runtime.h>

// ---------------- types ----------------
typedef __attribute__((ext_vector_type(8))) short short8;
typedef __attribute__((ext_vector_type(8))) unsigned short us8;
typedef __attribute__((ext_vector_type(4))) float f32x4;

#define C_DIM 1024
#define L_DIM 4096
#define B_DIM 8
#define H_DIM 8
#define HD 128
#define CHUNK 64
#define K2 2048   // split K (hi | lo)

// round-to-nearest-even fp32 -> bf16 (raw bits)
__device__ inline unsigned short bf16_hi(float f) {
    unsigned u = __float_as_uint(f);
    unsigned r = (u + 0x7FFFu + ((u >> 16) & 1u)) >> 16;
    return (unsigned short)r;
}
__device__ inline float bf16_to_f(unsigned short h) {
    return __uint_as_float(((unsigned)h) << 16);
}
__device__ inline void split2(float f, unsigned short& hi, unsigned short& lo) {
    hi = bf16_hi(f);
    lo = bf16_hi(f - bf16_to_f(hi));
}

// async global->LDS, 16B per lane; LDS dest = wave-uniform base + lane*16
__device__ inline void gld16(const unsigned short* gp, unsigned short* lp) {
    __builtin_amdgcn_global_load_lds(
        (const __attribute__((address_space(1))) unsigned int*)gp,
        (__attribute__((address_space(3))) unsigned int*)lp,
        16, 0, 0);
}

// ---------------- weight split+transpose: W[K][N] fp32 -> Wt[N][2K] bf16 ----------------
__global__ void split_w(const float* __restrict__ W, unsigned short* __restrict__ Wt) {
    __shared__ float tile[32][33];
    int nb = blockIdx.x * 32;  // n base
    int kb = blockIdx.y * 32;  // k base
    for (int i = 0; i < 4; ++i)
        tile[threadIdx.y + i * 8][threadIdx.x] =
            W[(size_t)(kb + threadIdx.y + i * 8) * C_DIM + nb + threadIdx.x];
    __syncthreads();
    for (int i = 0; i < 4; ++i) {
        int n = nb + threadIdx.y + i * 8;
        int k = kb + threadIdx.x;
        float v = tile[threadIdx.x][threadIdx.y + i * 8]; // = W[k][n]
        unsigned short hi, lo; split2(v, hi, lo);
        Wt[(size_t)n * K2 + k] = hi;
        Wt[(size_t)n * K2 + C_DIM + k] = lo;
    }
}

// ------------- x transpose+split: x[b][c][l] -> xsp[(b-b0)*L + l][2C] bf16 -------------
__global__ void split_x(const float* __restrict__ x, unsigned short* __restrict__ xsp, int b0) {
    __shared__ float tile[32][33];
    int lb = blockIdx.x * 32, cb = blockIdx.y * 32, bp = blockIdx.z;
    const float* xp = x + ((size_t)(b0 + bp) * C_DIM + cb) * L_DIM + lb;
    for (int i = 0; i < 4; ++i)
        tile[threadIdx.y + i * 8][threadIdx.x] = xp[(size_t)(threadIdx.y + i * 8) * L_DIM + threadIdx.x];
    __syncthreads();
    for (int i = 0; i < 4; ++i) {
        size_t row = (size_t)bp * L_DIM + lb + threadIdx.y + i * 8;
        int c = cb + threadIdx.x;
        float v = tile[threadIdx.x][threadIdx.y + i * 8]; // = x[b][c][l]
        unsigned short hi, lo; split2(v, hi, lo);
        xsp[row * K2 + c] = hi;
        xsp[row * K2 + C_DIM + c] = lo;
    }
}

// ---------------- bf16 MFMA GEMM: Y[M][N] = A[M][K] * Bt[N][K]^T + bias ----------------
// m97 structure: global_load_lds width-16 staging into LINEAR LDS (stride 64, no pad),
// 128x128 tile, BK=64, 4 waves, 16x16x32 MFMA, 2-barrier K-loop.
#define TM 128
#define TN 128
#define BK 64

__global__ __launch_bounds__(256) void gemm_bf16(
    const unsigned short* __restrict__ A,   // [M][K] k-contig bf16 bits
    const unsigned short* __restrict__ Bt,  // [N][K] k-contig bf16 bits
    const float* __restrict__ bias,         // [N]
    float* __restrict__ Y,                  // [M][N] fp32
    int M, int N, int K)
{
    __shared__ __align__(16) unsigned short As[TM * BK];
    __shared__ __align__(16) unsigned short Bs[TN * BK];
    int t = threadIdx.x;
    int m0 = blockIdx.y * TM, n0 = blockIdx.x * TN;
    int wave = t >> 6, lane = t & 63;
    int wr = wave >> 1, wc = wave & 1;
    int lm = lane & 15, quad = lane >> 4;

    f32x4 acc[4][4];
    for (int i = 0; i < 4; ++i)
        for (int j = 0; j < 4; ++j) { f32x4 z = {0.f, 0.f, 0.f, 0.f}; acc[i][j] = z; }

    // staging decomposition: per wave-call, 64 lanes write 1024B = 8 rows of 128B.
    // lane l -> row r0 + l/8, col-elem (l%8)*8 ; 4 waves x 4 calls = 128 rows.
    const int lrow8 = lane >> 3;        // 0..7
    const int lcol8 = (lane & 7) << 3;  // 0..56 (elems)
    const unsigned short* gA[4]; const unsigned short* gB[4];
    unsigned short* lA[4]; unsigned short* lB[4];
#pragma unroll
    for (int i = 0; i < 4; ++i) {
        int r0 = (wave * 4 + i) * 8;
        lA[i] = &As[r0 * BK];
        gA[i] = A + (size_t)(m0 + r0 + lrow8) * K + lcol8;
        lB[i] = &Bs[r0 * BK];
        gB[i] = Bt + (size_t)(n0 + r0 + lrow8) * K + lcol8;
    }

    for (int kt = 0; kt < K; kt += BK) {
#pragma unroll
        for (int i = 0; i < 4; ++i) {
            gld16(gA[i] + kt, lA[i]);
            gld16(gB[i] + kt, lB[i]);
        }
        __syncthreads();   // drains vmcnt: staged tile visible to all waves
#pragma unroll
        for (int s = 0; s < 2; ++s) {
            short8 af[4], bfr[4];
#pragma unroll
            for (int i = 0; i < 4; ++i)
                af[i] = *(const short8*)&As[(wr * 64 + i * 16 + lm) * BK + s * 32 + quad * 8];
#pragma unroll
            for (int j = 0; j < 4; ++j)
                bfr[j] = *(const short8*)&Bs[(wc * 64 + j * 16 + lm) * BK + s * 32 + quad * 8];
#pragma unroll
            for (int i = 0; i < 4; ++i)
#pragma unroll
                for (int j = 0; j < 4; ++j)
                    acc[i][j] = __builtin_amdgcn_mfma_f32_16x16x32_bf16(af[i], bfr[j], acc[i][j], 0, 0, 0);
        }
        __syncthreads();   // all waves done reading before next-iter staging overwrites
    }

    // epilogue: C/D mapping col=lane&15, row=quad*4+reg  [verified m89/m91]
#pragma unroll
    for (int i = 0; i < 4; ++i) {
        int row = m0 + wr * 64 + i * 16 + quad * 4;
#pragma unroll
        for (int j = 0; j < 4; ++j) {
            int col = n0 + wc * 64 + j * 16 + lm;
            float b = bias[col];
#pragma unroll
            for (int r = 0; r < 4; ++r)
                Y[(size_t)(row + r) * N + col] = acc[i][j][r] + b;
        }
    }
}

// ---------------- attention: one block per (b', chunk, head), fp32 ----------------
__global__ __launch_bounds__(256) void attn(
    const float* __restrict__ Qt, const float* __restrict__ Kt, const float* __restrict__ Vt,
    unsigned short* __restrict__ Osp)  // [BG*L][2C] bf16 split
{
    // bufQK: phase1 = Qhalf(64x65) + Khalf(64x64); phase3 = V(64x128); epi = O(64x129)
    __shared__ float bufQK[64 * 65 + 64 * 64];  // 8256 floats
    __shared__ float Ss[64 * 65];

    int t = threadIdx.x;
    int idx = blockIdx.x;
    int h = idx & 7;
    int chunk = (idx >> 3) & 63;
    int bp = idx >> 9;
    size_t rowbase = (size_t)bp * L_DIM + (size_t)chunk * CHUNK;
    const float* Qp = Qt + rowbase * C_DIM + h * HD;
    const float* Kp = Kt + rowbase * C_DIM + h * HD;
    const float* Vp = Vt + rowbase * C_DIM + h * HD;
    int wave = t >> 6, lane = t & 63;

    float sacc[16];
#pragma unroll
    for (int i = 0; i < 16; ++i) sacc[i] = 0.f;

    float* Qh = bufQK;            // stride 65 (lane-indexed reads: 2-way, free)
    float* Kh = bufQK + 64 * 65;  // stride 64 (wave-uniform reads: broadcast)

    for (int dh = 0; dh < HD; dh += 64) {
#pragma unroll
        for (int p = 0; p < 4; ++p) {
            int f = p * 256 + t;
            int row = f >> 4, col = (f & 15) * 4;
            float4 q4 = *(const float4*)&Qp[(size_t)row * C_DIM + dh + col];
            float4 k4 = *(const float4*)&Kp[(size_t)row * C_DIM + dh + col];
            Qh[row * 65 + col + 0] = q4.x; Qh[row * 65 + col + 1] = q4.y;
            Qh[row * 65 + col + 2] = q4.z; Qh[row * 65 + col + 3] = q4.w;
            *(float4*)&Kh[row * 64 + col] = k4;
        }
        __syncthreads();
        // lane = q row; this wave covers k in [wave*16, wave*16+16)
        for (int d = 0; d < 64; ++d) {
            float qv = Qh[lane * 65 + d];
            const float* kp = &Kh[(wave * 16) * 64 + d];
#pragma unroll
            for (int kk = 0; kk < 16; ++kk)
                sacc[kk] += qv * kp[kk * 64];
        }
        __syncthreads();
    }

    const float scale = 0.08838834764831845f;  // 1/sqrt(128)
#pragma unroll
    for (int kk = 0; kk < 16; ++kk)
        Ss[lane * 65 + wave * 16 + kk] = sacc[kk] * scale;
    __syncthreads();

    // softmax rows (threads 0..63), V load concurrent (bufQK is free now)
    float* Vs = bufQK;  // stride 128
#pragma unroll
    for (int p = 0; p < 8; ++p) {
        int f = p * 256 + t;
        int row = f >> 5, col = (f & 31) * 4;
        *(float4*)&Vs[row * 128 + col] = *(const float4*)&Vp[(size_t)row * C_DIM + col];
    }
    if (t < 64) {
        float mx = -1e30f;
        for (int k = 0; k < 64; ++k) mx = fmaxf(mx, Ss[t * 65 + k]);
        float sum = 0.f;
        for (int k = 0; k < 64; ++k) { float e = __expf(Ss[t * 65 + k] - mx); Ss[t * 65 + k] = e; sum += e; }
        float inv = 1.0f / sum;
        for (int k = 0; k < 64; ++k) Ss[t * 65 + k] *= inv;
    }
    __syncthreads();

    // O = P @ V ; lane = q row, wave covers d in [wave*32, wave*32+32)
    float oacc[32];
#pragma unroll
    for (int i = 0; i < 32; ++i) oacc[i] = 0.f;
    for (int k = 0; k < 64; ++k) {
        float p = Ss[lane * 65 + k];
        const float* vrow = &Vs[k * 128 + wave * 32];
#pragma unroll
        for (int dd = 0; dd < 32; ++dd)
            oacc[dd] += p * vrow[dd];
    }
    __syncthreads();  // before overwriting Vs with O staging
    float* Os = bufQK;  // stride 129 (conflict-free lane-row writes)
#pragma unroll
    for (int dd = 0; dd < 32; ++dd)
        Os[lane * 129 + wave * 32 + dd] = oacc[dd];
    __syncthreads();

    // write split-bf16 O: thread -> (row = t>>2, 32 contiguous d)
    {
        int row = t >> 2, dstart = (t & 3) * 32;
        size_t orow = (rowbase + row) * K2 + h * HD + dstart;
#pragma unroll
        for (int c = 0; c < 4; ++c) {
            us8 hv, lv;
#pragma unroll
            for (int i = 0; i < 8; ++i) {
                float v = Os[row * 129 + dstart + c * 8 + i];
                unsigned short hi, lo; split2(v, hi, lo);
                hv[i] = (short)hi; lv[i] = (short)lo;
            }
            *(us8*)&Osp[orow + c * 8] = hv;
            *(us8*)&Osp[orow + C_DIM + c * 8] = lv;
        }
    }
}

// ---------------- final transpose: Y[(b'*L + l)][c] -> out[b][c][l] ----------------
__global__ void trans_out(const float* __restrict__ Y, float* __restrict__ out, int b0) {
    __shared__ float tile[32][33];
    int lb = blockIdx.x * 32, cb = blockIdx.y * 32, bp = blockIdx.z;
    const float* Yp = Y + ((size_t)bp * L_DIM + lb) * C_DIM + cb;
    for (int i = 0; i < 4; ++i)
        tile[threadIdx.y + i * 8][threadIdx.x] = Yp[(size_t)(threadIdx.y + i * 8) * C_DIM + threadIdx.x];
    __syncthreads();
    float* op = out + ((size_t)(b0 + bp) * C_DIM + cb) * L_DIM + lb;
    for (int i = 0; i < 4; ++i)
        op[(size_t)(threadIdx.y + i * 8) * L_DIM + threadIdx.x] = tile[threadIdx.x][threadIdx.y + i * 8];
}

// ---------------- host ----------------
extern "C" void kernel_launch(void* const* d_in, const int* in_sizes, int n_in,
                              void* d_out, int out_size, void* d_ws, size_t ws_size,
                              hipStream_t stream) {
    const float* x  = (const float*)d_in[0];
    const float* Wq = (const float*)d_in[1];
    const float* bq = (const float*)d_in[2];
    const float* Wk = (const float*)d_in[3];
    const float* bk = (const float*)d_in[4];
    const float* Wv = (const float*)d_in[5];
    const float* bv = (const float*)d_in[6];
    const float* Wo = (const float*)d_in[7];
    const float* bo = (const float*)d_in[8];
    float* out = (float*)d_out;

    const size_t MB = 1024ull * 1024ull;
    char* base = (char*)d_ws;
    unsigned short* WspQ = (unsigned short*)(base + 0 * 4 * MB);
    unsigned short* WspK = (unsigned short*)(base + 1 * 4 * MB);
    unsigned short* WspV = (unsigned short*)(base + 2 * 4 * MB);
    unsigned short* WspO = (unsigned short*)(base + 3 * 4 * MB);

    // batch group size: ws need = 16MiB (weights) + BG*64MiB
    int BG = 8;
    while (BG > 1 && 16 * MB + (size_t)BG * 64 * MB > ws_size) BG >>= 1;

    char* p = base + 16 * MB;
    unsigned short* xsp = (unsigned short*)p;                 // [BG*L][2C] bf16; aliased as Osp
    float* Qt = (float*)(p + (size_t)BG * 16 * MB);           // [BG*L][C] fp32; aliased as Y
    float* Kt = (float*)(p + (size_t)BG * 32 * MB);
    float* Vt = (float*)(p + (size_t)BG * 48 * MB);

    dim3 tb(32, 8);
    split_w<<<dim3(32, 32), tb, 0, stream>>>(Wq, WspQ);
    split_w<<<dim3(32, 32), tb, 0, stream>>>(Wk, WspK);
    split_w<<<dim3(32, 32), tb, 0, stream>>>(Wv, WspV);
    split_w<<<dim3(32, 32), tb, 0, stream>>>(Wo, WspO);

    for (int b0 = 0; b0 < B_DIM; b0 += BG) {
        int M = BG * L_DIM;
        split_x<<<dim3(L_DIM / 32, C_DIM / 32, BG), tb, 0, stream>>>(x, xsp, b0);
        dim3 gg(C_DIM / TN, M / TM);
        gemm_bf16<<<gg, 256, 0, stream>>>(xsp, WspQ, bq, Qt, M, C_DIM, K2);
        gemm_bf16<<<gg, 256, 0, stream>>>(xsp, WspK, bk, Kt, M, C_DIM, K2);
        gemm_bf16<<<gg, 256, 0, stream>>>(xsp, WspV, bv, Vt, M, C_DIM, K2);
        attn<<<BG * (L_DIM / CHUNK) * H_DIM, 256, 0, stream>>>(Qt, Kt, Vt, xsp);
        gemm_bf16<<<gg, 256, 0, stream>>>(xsp, WspO, bo, Qt, M, C_DIM, K2);
        trans_out<<<dim3(L_DIM / 32, C_DIM / 32, BG), tb, 0, stream>>>(Qt, out, b0);
    }
}

// Round 2
// 1282.561 us; speedup vs baseline: 1.1019x; 1.1019x over previous
//
#include <hip/hip_runtime.h>

// ---------------- types ----------------
typedef __attribute__((ext_vector_type(8))) short short8;
typedef __attribute__((ext_vector_type(8))) unsigned short us8;
typedef __attribute__((ext_vector_type(4))) float f32x4;

#define C_DIM 1024
#define L_DIM 4096
#define B_DIM 8
#define H_DIM 8
#define HD 128
#define CHUNK 64
#define K2 2048   // split K (hi | lo)

// round-to-nearest-even fp32 -> bf16 (raw bits)
__device__ inline unsigned short bf16_hi(float f) {
    unsigned u = __float_as_uint(f);
    unsigned r = (u + 0x7FFFu + ((u >> 16) & 1u)) >> 16;
    return (unsigned short)r;
}
__device__ inline float bf16_to_f(unsigned short h) {
    return __uint_as_float(((unsigned)h) << 16);
}
__device__ inline void split2(float f, unsigned short& hi, unsigned short& lo) {
    hi = bf16_hi(f);
    lo = bf16_hi(f - bf16_to_f(hi));
}

// ---------------- weight split+transpose: W[K][N] fp32 -> Wt[N][2K] bf16 ----------------
__global__ void split_w(const float* __restrict__ W, unsigned short* __restrict__ Wt) {
    __shared__ float tile[32][33];
    int nb = blockIdx.x * 32;  // n base
    int kb = blockIdx.y * 32;  // k base
    for (int i = 0; i < 4; ++i)
        tile[threadIdx.y + i * 8][threadIdx.x] =
            W[(size_t)(kb + threadIdx.y + i * 8) * C_DIM + nb + threadIdx.x];
    __syncthreads();
    for (int i = 0; i < 4; ++i) {
        int n = nb + threadIdx.y + i * 8;
        int k = kb + threadIdx.x;
        float v = tile[threadIdx.x][threadIdx.y + i * 8]; // = W[k][n]
        unsigned short hi, lo; split2(v, hi, lo);
        Wt[(size_t)n * K2 + k] = hi;
        Wt[(size_t)n * K2 + C_DIM + k] = lo;
    }
}

// ------------- x transpose+split: x[b][c][l] -> xsp[(b-b0)*L + l][2C] bf16 -------------
// 64x64 tile, float4 loads (l-contig), us8 stores (c-contig). LDS stride 65:
// load-phase scatter and write-phase gather are both 2-way bank aliasing (free, m136).
__global__ __launch_bounds__(256) void split_x(const float* __restrict__ x,
                                               unsigned short* __restrict__ xsp, int b0) {
    __shared__ float tile[64][65];
    int t = threadIdx.x;
    int lb = blockIdx.x * 64, cb = blockIdx.y * 64, bp = blockIdx.z;
    const float* xp = x + ((size_t)(b0 + bp) * C_DIM + cb) * L_DIM + lb;
    // load: 4 passes x (16 c-rows x 16 threads x float4) -> 256B contiguous per row
#pragma unroll
    for (int p = 0; p < 4; ++p) {
        int cr = p * 16 + (t >> 4);
        int lo4 = (t & 15) * 4;
        float4 v = *(const float4*)&xp[(size_t)cr * L_DIM + lo4];
        tile[lo4 + 0][cr] = v.x;
        tile[lo4 + 1][cr] = v.y;
        tile[lo4 + 2][cr] = v.z;
        tile[lo4 + 3][cr] = v.w;
    }
    __syncthreads();
    // write: 2 passes x (32 l-rows x 8 threads x us8) -> 128B contiguous per row (x2 planes)
#pragma unroll
    for (int p = 0; p < 2; ++p) {
        int l = p * 32 + (t >> 3);
        int c8 = (t & 7) * 8;
        us8 hv, lv;
#pragma unroll
        for (int i = 0; i < 8; ++i) {
            unsigned short hi, lo; split2(tile[l][c8 + i], hi, lo);
            hv[i] = (short)hi; lv[i] = (short)lo;
        }
        size_t row = (size_t)bp * L_DIM + lb + l;
        *(us8*)&xsp[row * K2 + cb + c8] = hv;
        *(us8*)&xsp[row * K2 + C_DIM + cb + c8] = lv;
    }
}

// ---------------- bf16 MFMA GEMM: Y[M][N] = A[M][K] * Bt[N][K]^T + bias ----------------
// Reg-staged us8 -> padded LDS (LDSS=72: 2-way-only aliasing). tmode=1 fuses the final
// transpose: writes out[b][n][l] (float4 over 4 consecutive l = the 4 acc regs).
#define TM 128
#define TN 128
#define BK 64
#define LDSS 72   // LDS row stride (bf16 elems): +8 pad

__global__ __launch_bounds__(256) void gemm_bf16(
    const unsigned short* __restrict__ A,   // [M][K] k-contig bf16 bits
    const unsigned short* __restrict__ Bt,  // [N][K] k-contig bf16 bits
    const float* __restrict__ bias,         // [N]
    float* __restrict__ Y,                  // tmode0: [M][N] fp32 ; tmode1: out[b][N][L]
    int M, int N, int K, int tmode, int b0)
{
    __shared__ unsigned short As[TM * LDSS];
    __shared__ unsigned short Bs[TN * LDSS];
    int t = threadIdx.x;
    int m0 = blockIdx.y * TM, n0 = blockIdx.x * TN;
    int wave = t >> 6, lane = t & 63;
    int wr = wave >> 1, wc = wave & 1;
    int lm = lane & 15, quad = lane >> 4;

    f32x4 acc[4][4];
    for (int i = 0; i < 4; ++i)
        for (int j = 0; j < 4; ++j) { f32x4 z = {0.f, 0.f, 0.f, 0.f}; acc[i][j] = z; }

    const int lrow = t >> 3;        // 0..31
    const int lk = (t & 7) * 8;     // 0..56

    for (int kt = 0; kt < K; kt += BK) {
#pragma unroll
        for (int p = 0; p < 4; ++p) {
            int r = p * 32 + lrow;
            *(us8*)&As[r * LDSS + lk] = *(const us8*)&A[(size_t)(m0 + r) * K + kt + lk];
            *(us8*)&Bs[r * LDSS + lk] = *(const us8*)&Bt[(size_t)(n0 + r) * K + kt + lk];
        }
        __syncthreads();
#pragma unroll
        for (int s = 0; s < 2; ++s) {
            short8 af[4], bfr[4];
#pragma unroll
            for (int i = 0; i < 4; ++i)
                af[i] = *(const short8*)&As[(wr * 64 + i * 16 + lm) * LDSS + s * 32 + quad * 8];
#pragma unroll
            for (int j = 0; j < 4; ++j)
                bfr[j] = *(const short8*)&Bs[(wc * 64 + j * 16 + lm) * LDSS + s * 32 + quad * 8];
#pragma unroll
            for (int i = 0; i < 4; ++i)
#pragma unroll
                for (int j = 0; j < 4; ++j)
                    acc[i][j] = __builtin_amdgcn_mfma_f32_16x16x32_bf16(af[i], bfr[j], acc[i][j], 0, 0, 0);
        }
        __syncthreads();
    }

    // epilogue: C/D mapping col=lane&15, row=quad*4+reg  [verified m89/m91]
    if (tmode == 0) {
#pragma unroll
        for (int i = 0; i < 4; ++i) {
            int row = m0 + wr * 64 + i * 16 + quad * 4;
#pragma unroll
            for (int j = 0; j < 4; ++j) {
                int col = n0 + wc * 64 + j * 16 + lm;
                float b = bias[col];
#pragma unroll
                for (int r = 0; r < 4; ++r)
                    Y[(size_t)(row + r) * N + col] = acc[i][j][r] + b;
            }
        }
    } else {
        // fused transpose: row = (bp, l); 4 acc regs = 4 consecutive l -> one float4
#pragma unroll
        for (int i = 0; i < 4; ++i) {
            int row = m0 + wr * 64 + i * 16 + quad * 4;
            int bp = row >> 12;             // row / L_DIM
            int l = row & (L_DIM - 1);
#pragma unroll
            for (int j = 0; j < 4; ++j) {
                int col = n0 + wc * 64 + j * 16 + lm;
                float b = bias[col];
                float4 v;
                v.x = acc[i][j][0] + b; v.y = acc[i][j][1] + b;
                v.z = acc[i][j][2] + b; v.w = acc[i][j][3] + b;
                *(float4*)&Y[((size_t)(b0 + bp) * N + col) * L_DIM + l] = v;
            }
        }
    }
}

// ---------------- attention: one block per (b', chunk, head), fp32 ----------------
__global__ __launch_bounds__(256) void attn(
    const float* __restrict__ Qt, const float* __restrict__ Kt, const float* __restrict__ Vt,
    unsigned short* __restrict__ Osp)  // [BG*L][2C] bf16 split
{
    // bufQK: phase1 = Qhalf(64x65) + Khalf(64x64); phase3 = V(64x128); epi = O(64x129)
    __shared__ float bufQK[64 * 65 + 64 * 64];  // 8256 floats
    __shared__ float Ss[64 * 65];

    int t = threadIdx.x;
    int idx = blockIdx.x;
    int h = idx & 7;
    int chunk = (idx >> 3) & 63;
    int bp = idx >> 9;
    size_t rowbase = (size_t)bp * L_DIM + (size_t)chunk * CHUNK;
    const float* Qp = Qt + rowbase * C_DIM + h * HD;
    const float* Kp = Kt + rowbase * C_DIM + h * HD;
    const float* Vp = Vt + rowbase * C_DIM + h * HD;
    int wave = t >> 6, lane = t & 63;

    float sacc[16];
#pragma unroll
    for (int i = 0; i < 16; ++i) sacc[i] = 0.f;

    float* Qh = bufQK;            // stride 65 (lane-indexed reads: 2-way, free)
    float* Kh = bufQK + 64 * 65;  // stride 64 (wave-uniform reads: broadcast)

    for (int dh = 0; dh < HD; dh += 64) {
#pragma unroll
        for (int p = 0; p < 4; ++p) {
            int f = p * 256 + t;
            int row = f >> 4, col = (f & 15) * 4;
            float4 q4 = *(const float4*)&Qp[(size_t)row * C_DIM + dh + col];
            float4 k4 = *(const float4*)&Kp[(size_t)row * C_DIM + dh + col];
            Qh[row * 65 + col + 0] = q4.x; Qh[row * 65 + col + 1] = q4.y;
            Qh[row * 65 + col + 2] = q4.z; Qh[row * 65 + col + 3] = q4.w;
            *(float4*)&Kh[row * 64 + col] = k4;
        }
        __syncthreads();
        // lane = q row; this wave covers k in [wave*16, wave*16+16)
        for (int d = 0; d < 64; ++d) {
            float qv = Qh[lane * 65 + d];
            const float* kp = &Kh[(wave * 16) * 64 + d];
#pragma unroll
            for (int kk = 0; kk < 16; ++kk)
                sacc[kk] += qv * kp[kk * 64];
        }
        __syncthreads();
    }

    const float scale = 0.08838834764831845f;  // 1/sqrt(128)
#pragma unroll
    for (int kk = 0; kk < 16; ++kk)
        Ss[lane * 65 + wave * 16 + kk] = sacc[kk] * scale;
    __syncthreads();

    // softmax rows (threads 0..63), V load concurrent (bufQK is free now)
    float* Vs = bufQK;  // stride 128
#pragma unroll
    for (int p = 0; p < 8; ++p) {
        int f = p * 256 + t;
        int row = f >> 5, col = (f & 31) * 4;
        *(float4*)&Vs[row * 128 + col] = *(const float4*)&Vp[(size_t)row * C_DIM + col];
    }
    if (t < 64) {
        float mx = -1e30f;
        for (int k = 0; k < 64; ++k) mx = fmaxf(mx, Ss[t * 65 + k]);
        float sum = 0.f;
        for (int k = 0; k < 64; ++k) { float e = __expf(Ss[t * 65 + k] - mx); Ss[t * 65 + k] = e; sum += e; }
        float inv = 1.0f / sum;
        for (int k = 0; k < 64; ++k) Ss[t * 65 + k] *= inv;
    }
    __syncthreads();

    // O = P @ V ; lane = q row, wave covers d in [wave*32, wave*32+32)
    float oacc[32];
#pragma unroll
    for (int i = 0; i < 32; ++i) oacc[i] = 0.f;
    for (int k = 0; k < 64; ++k) {
        float p = Ss[lane * 65 + k];
        const float* vrow = &Vs[k * 128 + wave * 32];
#pragma unroll
        for (int dd = 0; dd < 32; ++dd)
            oacc[dd] += p * vrow[dd];
    }
    __syncthreads();  // before overwriting Vs with O staging
    float* Os = bufQK;  // stride 129 (conflict-free lane-row writes)
#pragma unroll
    for (int dd = 0; dd < 32; ++dd)
        Os[lane * 129 + wave * 32 + dd] = oacc[dd];
    __syncthreads();

    // write split-bf16 O: thread -> (row = t>>2, 32 contiguous d)
    {
        int row = t >> 2, dstart = (t & 3) * 32;
        size_t orow = (rowbase + row) * K2 + h * HD + dstart;
#pragma unroll
        for (int c = 0; c < 4; ++c) {
            us8 hv, lv;
#pragma unroll
            for (int i = 0; i < 8; ++i) {
                float v = Os[row * 129 + dstart + c * 8 + i];
                unsigned short hi, lo; split2(v, hi, lo);
                hv[i] = (short)hi; lv[i] = (short)lo;
            }
            *(us8*)&Osp[orow + c * 8] = hv;
            *(us8*)&Osp[orow + C_DIM + c * 8] = lv;
        }
    }
}

// ---------------- host ----------------
extern "C" void kernel_launch(void* const* d_in, const int* in_sizes, int n_in,
                              void* d_out, int out_size, void* d_ws, size_t ws_size,
                              hipStream_t stream) {
    const float* x  = (const float*)d_in[0];
    const float* Wq = (const float*)d_in[1];
    const float* bq = (const float*)d_in[2];
    const float* Wk = (const float*)d_in[3];
    const float* bk = (const float*)d_in[4];
    const float* Wv = (const float*)d_in[5];
    const float* bv = (const float*)d_in[6];
    const float* Wo = (const float*)d_in[7];
    const float* bo = (const float*)d_in[8];
    float* out = (float*)d_out;

    const size_t MB = 1024ull * 1024ull;
    char* base = (char*)d_ws;
    unsigned short* WspQ = (unsigned short*)(base + 0 * 4 * MB);
    unsigned short* WspK = (unsigned short*)(base + 1 * 4 * MB);
    unsigned short* WspV = (unsigned short*)(base + 2 * 4 * MB);
    unsigned short* WspO = (unsigned short*)(base + 3 * 4 * MB);

    // batch group size: ws need = 16MiB (weights) + BG*64MiB
    int BG = 8;
    while (BG > 1 && 16 * MB + (size_t)BG * 64 * MB > ws_size) BG >>= 1;

    char* p = base + 16 * MB;
    unsigned short* xsp = (unsigned short*)p;                 // [BG*L][2C] bf16; aliased as Osp
    float* Qt = (float*)(p + (size_t)BG * 16 * MB);           // [BG*L][C] fp32
    float* Kt = (float*)(p + (size_t)BG * 32 * MB);
    float* Vt = (float*)(p + (size_t)BG * 48 * MB);

    dim3 tb(32, 8);
    split_w<<<dim3(32, 32), tb, 0, stream>>>(Wq, WspQ);
    split_w<<<dim3(32, 32), tb, 0, stream>>>(Wk, WspK);
    split_w<<<dim3(32, 32), tb, 0, stream>>>(Wv, WspV);
    split_w<<<dim3(32, 32), tb, 0, stream>>>(Wo, WspO);

    for (int b0 = 0; b0 < B_DIM; b0 += BG) {
        int M = BG * L_DIM;
        split_x<<<dim3(L_DIM / 64, C_DIM / 64, BG), 256, 0, stream>>>(x, xsp, b0);
        dim3 gg(C_DIM / TN, M / TM);
        gemm_bf16<<<gg, 256, 0, stream>>>(xsp, WspQ, bq, Qt, M, C_DIM, K2, 0, 0);
        gemm_bf16<<<gg, 256, 0, stream>>>(xsp, WspK, bk, Kt, M, C_DIM, K2, 0, 0);
        gemm_bf16<<<gg, 256, 0, stream>>>(xsp, WspV, bv, Vt, M, C_DIM, K2, 0, 0);
        attn<<<BG * (L_DIM / CHUNK) * H_DIM, 256, 0, stream>>>(Qt, Kt, Vt, xsp);
        // O projection with fused transpose: writes out[b][c][l] directly
        gemm_bf16<<<gg, 256, 0, stream>>>(xsp, WspO, bo, out, M, C_DIM, K2, 1, b0);
    }
}

// Round 3
// 894.779 us; speedup vs baseline: 1.5795x; 1.4334x over previous
//
#include <hip/hip_runtime.h>

// ---------------- types ----------------
typedef __attribute__((ext_vector_type(8))) short short8;
typedef __attribute__((ext_vector_type(8))) unsigned short us8;
typedef __attribute__((ext_vector_type(4))) float f32x4;

#define C_DIM 1024
#define L_DIM 4096
#define B_DIM 8
#define H_DIM 8
#define HD 128
#define CHUNK 64
// K for all GEMMs is C_DIM (pure bf16; the old hi|lo split-K computed
// hi*hi + lo*lo -- the lo*lo term is ~1e-5 absolute, numerically dead weight)

// round-to-nearest-even fp32 -> bf16 (raw bits)
__device__ inline unsigned short bf16_hi(float f) {
    unsigned u = __float_as_uint(f);
    unsigned r = (u + 0x7FFFu + ((u >> 16) & 1u)) >> 16;
    return (unsigned short)r;
}

// ---------------- weight transpose+round: W[K][N] fp32 -> Wt[N][K] bf16 ----------------
__global__ void split_w(const float* __restrict__ W, unsigned short* __restrict__ Wt) {
    __shared__ float tile[32][33];
    int nb = blockIdx.x * 32;  // n base
    int kb = blockIdx.y * 32;  // k base
    for (int i = 0; i < 4; ++i)
        tile[threadIdx.y + i * 8][threadIdx.x] =
            W[(size_t)(kb + threadIdx.y + i * 8) * C_DIM + nb + threadIdx.x];
    __syncthreads();
    for (int i = 0; i < 4; ++i) {
        int n = nb + threadIdx.y + i * 8;
        int k = kb + threadIdx.x;
        float v = tile[threadIdx.x][threadIdx.y + i * 8]; // = W[k][n]
        Wt[(size_t)n * C_DIM + k] = bf16_hi(v);
    }
}

// ------------- x transpose+round: x[b][c][l] -> xsp[(b-b0)*L + l][C] bf16 -------------
// 64x64 tile, float4 loads (l-contig), us8 stores (c-contig). LDS stride 65:
// load-phase scatter and write-phase gather are both 2-way bank aliasing (free, m136).
__global__ __launch_bounds__(256) void split_x(const float* __restrict__ x,
                                               unsigned short* __restrict__ xsp, int b0) {
    __shared__ float tile[64][65];
    int t = threadIdx.x;
    int lb = blockIdx.x * 64, cb = blockIdx.y * 64, bp = blockIdx.z;
    const float* xp = x + ((size_t)(b0 + bp) * C_DIM + cb) * L_DIM + lb;
#pragma unroll
    for (int p = 0; p < 4; ++p) {
        int cr = p * 16 + (t >> 4);
        int lo4 = (t & 15) * 4;
        float4 v = *(const float4*)&xp[(size_t)cr * L_DIM + lo4];
        tile[lo4 + 0][cr] = v.x;
        tile[lo4 + 1][cr] = v.y;
        tile[lo4 + 2][cr] = v.z;
        tile[lo4 + 3][cr] = v.w;
    }
    __syncthreads();
#pragma unroll
    for (int p = 0; p < 2; ++p) {
        int l = p * 32 + (t >> 3);
        int c8 = (t & 7) * 8;
        us8 hv;
#pragma unroll
        for (int i = 0; i < 8; ++i)
            hv[i] = (short)bf16_hi(tile[l][c8 + i]);
        size_t row = (size_t)bp * L_DIM + lb + l;
        *(us8*)&xsp[row * C_DIM + cb + c8] = hv;
    }
}

// ---------------- bf16 MFMA GEMM: Y[M][N] = A[M][K] * Bt[N][K]^T + bias ----------------
// Reg-staged us8 -> padded LDS (LDSS=72: 2-way-only aliasing). tmode=1 fuses the final
// transpose: writes out[b][n][l] (float4 over 4 consecutive l = the 4 acc regs).
#define TM 128
#define TN 128
#define BK 64
#define LDSS 72   // LDS row stride (bf16 elems): +8 pad

__global__ __launch_bounds__(256) void gemm_bf16(
    const unsigned short* __restrict__ A,   // [M][K] k-contig bf16 bits
    const unsigned short* __restrict__ Bt,  // [N][K] k-contig bf16 bits
    const float* __restrict__ bias,         // [N]
    float* __restrict__ Y,                  // tmode0: [M][N] fp32 ; tmode1: out[b][N][L]
    int M, int N, int K, int tmode, int b0)
{
    __shared__ unsigned short As[TM * LDSS];
    __shared__ unsigned short Bs[TN * LDSS];
    int t = threadIdx.x;
    int m0 = blockIdx.y * TM, n0 = blockIdx.x * TN;
    int wave = t >> 6, lane = t & 63;
    int wr = wave >> 1, wc = wave & 1;
    int lm = lane & 15, quad = lane >> 4;

    f32x4 acc[4][4];
    for (int i = 0; i < 4; ++i)
        for (int j = 0; j < 4; ++j) { f32x4 z = {0.f, 0.f, 0.f, 0.f}; acc[i][j] = z; }

    const int lrow = t >> 3;        // 0..31
    const int lk = (t & 7) * 8;     // 0..56

    for (int kt = 0; kt < K; kt += BK) {
#pragma unroll
        for (int p = 0; p < 4; ++p) {
            int r = p * 32 + lrow;
            *(us8*)&As[r * LDSS + lk] = *(const us8*)&A[(size_t)(m0 + r) * K + kt + lk];
            *(us8*)&Bs[r * LDSS + lk] = *(const us8*)&Bt[(size_t)(n0 + r) * K + kt + lk];
        }
        __syncthreads();
#pragma unroll
        for (int s = 0; s < 2; ++s) {
            short8 af[4], bfr[4];
#pragma unroll
            for (int i = 0; i < 4; ++i)
                af[i] = *(const short8*)&As[(wr * 64 + i * 16 + lm) * LDSS + s * 32 + quad * 8];
#pragma unroll
            for (int j = 0; j < 4; ++j)
                bfr[j] = *(const short8*)&Bs[(wc * 64 + j * 16 + lm) * LDSS + s * 32 + quad * 8];
#pragma unroll
            for (int i = 0; i < 4; ++i)
#pragma unroll
                for (int j = 0; j < 4; ++j)
                    acc[i][j] = __builtin_amdgcn_mfma_f32_16x16x32_bf16(af[i], bfr[j], acc[i][j], 0, 0, 0);
        }
        __syncthreads();
    }

    // epilogue: C/D mapping col=lane&15, row=quad*4+reg  [verified m89/m91]
    if (tmode == 0) {
#pragma unroll
        for (int i = 0; i < 4; ++i) {
            int row = m0 + wr * 64 + i * 16 + quad * 4;
#pragma unroll
            for (int j = 0; j < 4; ++j) {
                int col = n0 + wc * 64 + j * 16 + lm;
                float b = bias[col];
#pragma unroll
                for (int r = 0; r < 4; ++r)
                    Y[(size_t)(row + r) * N + col] = acc[i][j][r] + b;
            }
        }
    } else {
        // fused transpose: row = (bp, l); 4 acc regs = 4 consecutive l -> one float4
#pragma unroll
        for (int i = 0; i < 4; ++i) {
            int row = m0 + wr * 64 + i * 16 + quad * 4;
            int bp = row >> 12;             // row / L_DIM
            int l = row & (L_DIM - 1);
#pragma unroll
            for (int j = 0; j < 4; ++j) {
                int col = n0 + wc * 64 + j * 16 + lm;
                float b = bias[col];
                float4 v;
                v.x = acc[i][j][0] + b; v.y = acc[i][j][1] + b;
                v.z = acc[i][j][2] + b; v.w = acc[i][j][3] + b;
                *(float4*)&Y[((size_t)(b0 + bp) * N + col) * L_DIM + l] = v;
            }
        }
    }
}

// ---------------- attention: one block per (b', chunk, head), fp32 ----------------
__global__ __launch_bounds__(256) void attn(
    const float* __restrict__ Qt, const float* __restrict__ Kt, const float* __restrict__ Vt,
    unsigned short* __restrict__ Osp)  // [BG*L][C] bf16
{
    // bufQK: phase1 = Qhalf(64x65) + Khalf(64x64); phase3 = V(64x128); epi = O(64x129)
    __shared__ float bufQK[64 * 65 + 64 * 64];  // 8256 floats
    __shared__ float Ss[64 * 65];

    int t = threadIdx.x;
    int idx = blockIdx.x;
    int h = idx & 7;
    int chunk = (idx >> 3) & 63;
    int bp = idx >> 9;
    size_t rowbase = (size_t)bp * L_DIM + (size_t)chunk * CHUNK;
    const float* Qp = Qt + rowbase * C_DIM + h * HD;
    const float* Kp = Kt + rowbase * C_DIM + h * HD;
    const float* Vp = Vt + rowbase * C_DIM + h * HD;
    int wave = t >> 6, lane = t & 63;

    float sacc[16];
#pragma unroll
    for (int i = 0; i < 16; ++i) sacc[i] = 0.f;

    float* Qh = bufQK;            // stride 65 (lane-indexed reads: 2-way, free)
    float* Kh = bufQK + 64 * 65;  // stride 64 (wave-uniform reads: broadcast)

    for (int dh = 0; dh < HD; dh += 64) {
#pragma unroll
        for (int p = 0; p < 4; ++p) {
            int f = p * 256 + t;
            int row = f >> 4, col = (f & 15) * 4;
            float4 q4 = *(const float4*)&Qp[(size_t)row * C_DIM + dh + col];
            float4 k4 = *(const float4*)&Kp[(size_t)row * C_DIM + dh + col];
            Qh[row * 65 + col + 0] = q4.x; Qh[row * 65 + col + 1] = q4.y;
            Qh[row * 65 + col + 2] = q4.z; Qh[row * 65 + col + 3] = q4.w;
            *(float4*)&Kh[row * 64 + col] = k4;
        }
        __syncthreads();
        // lane = q row; this wave covers k in [wave*16, wave*16+16)
        for (int d = 0; d < 64; ++d) {
            float qv = Qh[lane * 65 + d];
            const float* kp = &Kh[(wave * 16) * 64 + d];
#pragma unroll
            for (int kk = 0; kk < 16; ++kk)
                sacc[kk] += qv * kp[kk * 64];
        }
        __syncthreads();
    }

    const float scale = 0.08838834764831845f;  // 1/sqrt(128)
#pragma unroll
    for (int kk = 0; kk < 16; ++kk)
        Ss[lane * 65 + wave * 16 + kk] = sacc[kk] * scale;
    __syncthreads();

    // softmax rows (threads 0..63), V load concurrent (bufQK is free now)
    float* Vs = bufQK;  // stride 128
#pragma unroll
    for (int p = 0; p < 8; ++p) {
        int f = p * 256 + t;
        int row = f >> 5, col = (f & 31) * 4;
        *(float4*)&Vs[row * 128 + col] = *(const float4*)&Vp[(size_t)row * C_DIM + col];
    }
    if (t < 64) {
        float mx = -1e30f;
        for (int k = 0; k < 64; ++k) mx = fmaxf(mx, Ss[t * 65 + k]);
        float sum = 0.f;
        for (int k = 0; k < 64; ++k) { float e = __expf(Ss[t * 65 + k] - mx); Ss[t * 65 + k] = e; sum += e; }
        float inv = 1.0f / sum;
        for (int k = 0; k < 64; ++k) Ss[t * 65 + k] *= inv;
    }
    __syncthreads();

    // O = P @ V ; lane = q row, wave covers d in [wave*32, wave*32+32)
    float oacc[32];
#pragma unroll
    for (int i = 0; i < 32; ++i) oacc[i] = 0.f;
    for (int k = 0; k < 64; ++k) {
        float p = Ss[lane * 65 + k];
        const float* vrow = &Vs[k * 128 + wave * 32];
#pragma unroll
        for (int dd = 0; dd < 32; ++dd)
            oacc[dd] += p * vrow[dd];
    }
    __syncthreads();  // before overwriting Vs with O staging
    float* Os = bufQK;  // stride 129 (conflict-free lane-row writes)
#pragma unroll
    for (int dd = 0; dd < 32; ++dd)
        Os[lane * 129 + wave * 32 + dd] = oacc[dd];
    __syncthreads();

    // write bf16 O: thread -> (row = t>>2, 32 contiguous d)
    {
        int row = t >> 2, dstart = (t & 3) * 32;
        size_t orow = (rowbase + row) * C_DIM + h * HD + dstart;
#pragma unroll
        for (int c = 0; c < 4; ++c) {
            us8 hv;
#pragma unroll
            for (int i = 0; i < 8; ++i)
                hv[i] = (short)bf16_hi(Os[row * 129 + dstart + c * 8 + i]);
            *(us8*)&Osp[orow + c * 8] = hv;
        }
    }
}

// ---------------- host ----------------
extern "C" void kernel_launch(void* const* d_in, const int* in_sizes, int n_in,
                              void* d_out, int out_size, void* d_ws, size_t ws_size,
                              hipStream_t stream) {
    const float* x  = (const float*)d_in[0];
    const float* Wq = (const float*)d_in[1];
    const float* bq = (const float*)d_in[2];
    const float* Wk = (const float*)d_in[3];
    const float* bk = (const float*)d_in[4];
    const float* Wv = (const float*)d_in[5];
    const float* bv = (const float*)d_in[6];
    const float* Wo = (const float*)d_in[7];
    const float* bo = (const float*)d_in[8];
    float* out = (float*)d_out;

    const size_t MB = 1024ull * 1024ull;
    char* base = (char*)d_ws;
    unsigned short* WspQ = (unsigned short*)(base + 0 * 2 * MB);
    unsigned short* WspK = (unsigned short*)(base + 1 * 2 * MB);
    unsigned short* WspV = (unsigned short*)(base + 2 * 2 * MB);
    unsigned short* WspO = (unsigned short*)(base + 3 * 2 * MB);

    // batch group size: ws need = 16MiB (weights+pad) + BG*56MiB
    int BG = 8;
    while (BG > 1 && 16 * MB + (size_t)BG * 56 * MB > ws_size) BG >>= 1;

    char* p = base + 16 * MB;
    unsigned short* xsp = (unsigned short*)p;                 // [BG*L][C] bf16; aliased as Osp
    float* Qt = (float*)(p + (size_t)BG * 8 * MB);            // [BG*L][C] fp32
    float* Kt = (float*)(p + (size_t)BG * 24 * MB);
    float* Vt = (float*)(p + (size_t)BG * 40 * MB);

    dim3 tb(32, 8);
    split_w<<<dim3(32, 32), tb, 0, stream>>>(Wq, WspQ);
    split_w<<<dim3(32, 32), tb, 0, stream>>>(Wk, WspK);
    split_w<<<dim3(32, 32), tb, 0, stream>>>(Wv, WspV);
    split_w<<<dim3(32, 32), tb, 0, stream>>>(Wo, WspO);

    for (int b0 = 0; b0 < B_DIM; b0 += BG) {
        int M = BG * L_DIM;
        split_x<<<dim3(L_DIM / 64, C_DIM / 64, BG), 256, 0, stream>>>(x, xsp, b0);
        dim3 gg(C_DIM / TN, M / TM);
        gemm_bf16<<<gg, 256, 0, stream>>>(xsp, WspQ, bq, Qt, M, C_DIM, C_DIM, 0, 0);
        gemm_bf16<<<gg, 256, 0, stream>>>(xsp, WspK, bk, Kt, M, C_DIM, C_DIM, 0, 0);
        gemm_bf16<<<gg, 256, 0, stream>>>(xsp, WspV, bv, Vt, M, C_DIM, C_DIM, 0, 0);
        attn<<<BG * (L_DIM / CHUNK) * H_DIM, 256, 0, stream>>>(Qt, Kt, Vt, xsp);
        // O projection with fused transpose: writes out[b][c][l] directly
        gemm_bf16<<<gg, 256, 0, stream>>>(xsp, WspO, bo, out, M, C_DIM, C_DIM, 1, b0);
    }
}

// Round 4
// 801.261 us; speedup vs baseline: 1.7638x; 1.1167x over previous
//
#include <hip/hip_runtime.h>

// ---------------- types ----------------
typedef __attribute__((ext_vector_type(8))) short short8;
typedef __attribute__((ext_vector_type(8))) unsigned short us8;
typedef __attribute__((ext_vector_type(4))) float f32x4;

#define C_DIM 1024
#define L_DIM 4096
#define B_DIM 8
#define H_DIM 8
#define HD 128
#define CHUNK 64

// round-to-nearest-even fp32 -> bf16 (raw bits)
__device__ inline unsigned short bf16_hi(float f) {
    unsigned u = __float_as_uint(f);
    unsigned r = (u + 0x7FFFu + ((u >> 16) & 1u)) >> 16;
    return (unsigned short)r;
}
__device__ inline us8 pack8(float4 a, float4 b) {
    us8 v;
    v[0] = bf16_hi(a.x); v[1] = bf16_hi(a.y); v[2] = bf16_hi(a.z); v[3] = bf16_hi(a.w);
    v[4] = bf16_hi(b.x); v[5] = bf16_hi(b.y); v[6] = bf16_hi(b.z); v[7] = bf16_hi(b.w);
    return v;
}

// ---------------- weight transpose+round: W[K][N] fp32 -> Wt[N][K] bf16 ----------------
__global__ void split_w(const float* __restrict__ W, unsigned short* __restrict__ Wt) {
    __shared__ float tile[32][33];
    int nb = blockIdx.x * 32;  // n base
    int kb = blockIdx.y * 32;  // k base
    for (int i = 0; i < 4; ++i)
        tile[threadIdx.y + i * 8][threadIdx.x] =
            W[(size_t)(kb + threadIdx.y + i * 8) * C_DIM + nb + threadIdx.x];
    __syncthreads();
    for (int i = 0; i < 4; ++i) {
        int n = nb + threadIdx.y + i * 8;
        int k = kb + threadIdx.x;
        float v = tile[threadIdx.x][threadIdx.y + i * 8]; // = W[k][n]
        Wt[(size_t)n * C_DIM + k] = bf16_hi(v);
    }
}

// ------------- x transpose+round: x[b][c][l] -> xsp[(b-b0)*L + l][C] bf16 -------------
__global__ __launch_bounds__(256) void split_x(const float* __restrict__ x,
                                               unsigned short* __restrict__ xsp, int b0) {
    __shared__ float tile[64][65];
    int t = threadIdx.x;
    int lb = blockIdx.x * 64, cb = blockIdx.y * 64, bp = blockIdx.z;
    const float* xp = x + ((size_t)(b0 + bp) * C_DIM + cb) * L_DIM + lb;
#pragma unroll
    for (int p = 0; p < 4; ++p) {
        int cr = p * 16 + (t >> 4);
        int lo4 = (t & 15) * 4;
        float4 v = *(const float4*)&xp[(size_t)cr * L_DIM + lo4];
        tile[lo4 + 0][cr] = v.x;
        tile[lo4 + 1][cr] = v.y;
        tile[lo4 + 2][cr] = v.z;
        tile[lo4 + 3][cr] = v.w;
    }
    __syncthreads();
#pragma unroll
    for (int p = 0; p < 2; ++p) {
        int l = p * 32 + (t >> 3);
        int c8 = (t & 7) * 8;
        us8 hv;
#pragma unroll
        for (int i = 0; i < 8; ++i)
            hv[i] = bf16_hi(tile[l][c8 + i]);
        size_t row = (size_t)bp * L_DIM + lb + l;
        *(us8*)&xsp[row * C_DIM + cb + c8] = hv;
    }
}

// ---------------- bf16 MFMA GEMM: Y[M][N] = A[M][K] * Bt[N][K]^T + bias ----------------
#define TM 128
#define TN 128
#define BK 64
#define LDSS 72   // LDS row stride (bf16 elems): +8 pad -> 2-way-only aliasing

__global__ __launch_bounds__(256) void gemm_bf16(
    const unsigned short* __restrict__ A,   // [M][K] k-contig bf16 bits
    const unsigned short* __restrict__ Bt,  // [N][K] k-contig bf16 bits
    const float* __restrict__ bias,         // [N]
    float* __restrict__ Y,                  // tmode0: [M][N] fp32 ; tmode1: [b][N][L] fp32
    int M, int N, int K, int tmode, int b0)
{
    __shared__ unsigned short As[TM * LDSS];
    __shared__ unsigned short Bs[TN * LDSS];
    int t = threadIdx.x;
    int m0 = blockIdx.y * TM, n0 = blockIdx.x * TN;
    int wave = t >> 6, lane = t & 63;
    int wr = wave >> 1, wc = wave & 1;
    int lm = lane & 15, quad = lane >> 4;

    f32x4 acc[4][4];
    for (int i = 0; i < 4; ++i)
        for (int j = 0; j < 4; ++j) { f32x4 z = {0.f, 0.f, 0.f, 0.f}; acc[i][j] = z; }

    const int lrow = t >> 3;        // 0..31
    const int lk = (t & 7) * 8;     // 0..56

    for (int kt = 0; kt < K; kt += BK) {
#pragma unroll
        for (int p = 0; p < 4; ++p) {
            int r = p * 32 + lrow;
            *(us8*)&As[r * LDSS + lk] = *(const us8*)&A[(size_t)(m0 + r) * K + kt + lk];
            *(us8*)&Bs[r * LDSS + lk] = *(const us8*)&Bt[(size_t)(n0 + r) * K + kt + lk];
        }
        __syncthreads();
#pragma unroll
        for (int s = 0; s < 2; ++s) {
            short8 af[4], bfr[4];
#pragma unroll
            for (int i = 0; i < 4; ++i)
                af[i] = *(const short8*)&As[(wr * 64 + i * 16 + lm) * LDSS + s * 32 + quad * 8];
#pragma unroll
            for (int j = 0; j < 4; ++j)
                bfr[j] = *(const short8*)&Bs[(wc * 64 + j * 16 + lm) * LDSS + s * 32 + quad * 8];
#pragma unroll
            for (int i = 0; i < 4; ++i)
#pragma unroll
                for (int j = 0; j < 4; ++j)
                    acc[i][j] = __builtin_amdgcn_mfma_f32_16x16x32_bf16(af[i], bfr[j], acc[i][j], 0, 0, 0);
        }
        __syncthreads();
    }

    // epilogue: C/D mapping col=lane&15, row=quad*4+reg  [verified m89/m91]
    if (tmode == 0) {
#pragma unroll
        for (int i = 0; i < 4; ++i) {
            int row = m0 + wr * 64 + i * 16 + quad * 4;
#pragma unroll
            for (int j = 0; j < 4; ++j) {
                int col = n0 + wc * 64 + j * 16 + lm;
                float b = bias[col];
#pragma unroll
                for (int r = 0; r < 4; ++r)
                    Y[(size_t)(row + r) * N + col] = acc[i][j][r] + b;
            }
        }
    } else {
        // fused transpose: row = (bp, l); 4 acc regs = 4 consecutive l -> one float4
#pragma unroll
        for (int i = 0; i < 4; ++i) {
            int row = m0 + wr * 64 + i * 16 + quad * 4;
            int bp = row >> 12;             // row / L_DIM
            int l = row & (L_DIM - 1);
#pragma unroll
            for (int j = 0; j < 4; ++j) {
                int col = n0 + wc * 64 + j * 16 + lm;
                float b = bias[col];
                float4 v;
                v.x = acc[i][j][0] + b; v.y = acc[i][j][1] + b;
                v.z = acc[i][j][2] + b; v.w = acc[i][j][3] + b;
                *(float4*)&Y[((size_t)(b0 + bp) * N + col) * L_DIM + l] = v;
            }
        }
    }
}

// ---------------- attention (MFMA): one block per (b', chunk, head) ----------------
// Q,K fp32 [M][C]; V^T fp32 [BG][C][L] (from the V-GEMM's tmode=1 epilogue).
// Fragment mapping identical to gemm_bf16 (A/B: row=lane&15, k=quad*8+ks*32;
// C/D: col=lane&15, row=quad*4+reg).
__global__ __launch_bounds__(256) void attn(
    const float* __restrict__ Qt, const float* __restrict__ Kt, const float* __restrict__ Vt,
    unsigned short* __restrict__ Osp)  // [BG*L][C] bf16
{
    __shared__ __align__(16) char smem[53248];
    unsigned short* Qs = (unsigned short*)smem;            // [64][136] bf16
    unsigned short* Ks = (unsigned short*)(smem + 17408);  // [64][136] bf16
    unsigned short* Vs = (unsigned short*)(smem + 34816);  // [128][72] bf16 (V^T: row=d, col=k)
    float* Ss = (float*)smem;                              // [64][68] fp32, overlays Qs
    unsigned short* Ps = (unsigned short*)(smem + 17408);  // [64][72] bf16, overlays Ks
    float* Os = (float*)smem;                              // [64][132] fp32, overlays Qs+Ks

    int t = threadIdx.x;
    int idx = blockIdx.x;
    int h = idx & 7;
    int chunk = (idx >> 3) & 63;
    int bp = idx >> 9;
    size_t rowbase = (size_t)bp * L_DIM + (size_t)chunk * CHUNK;
    const float* Qp = Qt + rowbase * C_DIM + h * HD;
    const float* Kp = Kt + rowbase * C_DIM + h * HD;
    const float* Vp = Vt + ((size_t)bp * C_DIM + h * HD) * L_DIM + (size_t)chunk * CHUNK;
    int wave = t >> 6, lane = t & 63;
    int lm = lane & 15, quad = lane >> 4;

    // ---- stage Q,K (64 rows x 128 c) and V^T (128 d-rows x 64 k) -> bf16 LDS ----
#pragma unroll
    for (int p = 0; p < 4; ++p) {
        int row = p * 16 + (t >> 4);
        int c8 = (t & 15) * 8;
        float4 a = *(const float4*)&Qp[(size_t)row * C_DIM + c8];
        float4 b = *(const float4*)&Qp[(size_t)row * C_DIM + c8 + 4];
        *(us8*)&Qs[row * 136 + c8] = pack8(a, b);
        a = *(const float4*)&Kp[(size_t)row * C_DIM + c8];
        b = *(const float4*)&Kp[(size_t)row * C_DIM + c8 + 4];
        *(us8*)&Ks[row * 136 + c8] = pack8(a, b);
    }
#pragma unroll
    for (int p = 0; p < 4; ++p) {
        int row = p * 32 + (t >> 3);   // d 0..127
        int c8 = (t & 7) * 8;          // k 0..56
        float4 a = *(const float4*)&Vp[(size_t)row * L_DIM + c8];
        float4 b = *(const float4*)&Vp[(size_t)row * L_DIM + c8 + 4];
        *(us8*)&Vs[row * 72 + c8] = pack8(a, b);
    }
    __syncthreads();

    // ---- QK^T: S[64 q][64 k]; wave owns cols wave*16..+16 ----
    f32x4 sa[4];
#pragma unroll
    for (int i = 0; i < 4; ++i) { f32x4 z = {0.f, 0.f, 0.f, 0.f}; sa[i] = z; }
#pragma unroll
    for (int ks = 0; ks < 4; ++ks) {
        short8 bfr = *(const short8*)&Ks[(wave * 16 + lm) * 136 + ks * 32 + quad * 8];
#pragma unroll
        for (int i = 0; i < 4; ++i) {
            short8 af = *(const short8*)&Qs[(i * 16 + lm) * 136 + ks * 32 + quad * 8];
            sa[i] = __builtin_amdgcn_mfma_f32_16x16x32_bf16(af, bfr, sa[i], 0, 0, 0);
        }
    }
    __syncthreads();   // all QK^T LDS reads done before S overlays Qs

    const float scale = 0.08838834764831845f;  // 1/sqrt(128)
#pragma unroll
    for (int i = 0; i < 4; ++i)
#pragma unroll
        for (int r = 0; r < 4; ++r)
            Ss[(i * 16 + quad * 4 + r) * 68 + wave * 16 + lm] = sa[i][r] * scale;
    __syncthreads();

    // ---- softmax: 4 threads per row, 16 cols each, 4-lane shuffle reduce ----
    {
        int srow = t >> 2, scb = (t & 3) * 16;
        float v[16];
        float mx = -1e30f;
#pragma unroll
        for (int q = 0; q < 4; ++q) {
            float4 f = *(const float4*)&Ss[srow * 68 + scb + q * 4];
            v[q * 4 + 0] = f.x; v[q * 4 + 1] = f.y; v[q * 4 + 2] = f.z; v[q * 4 + 3] = f.w;
            mx = fmaxf(fmaxf(fmaxf(mx, f.x), fmaxf(f.y, f.z)), f.w);
        }
        mx = fmaxf(mx, __shfl_xor(mx, 1));
        mx = fmaxf(mx, __shfl_xor(mx, 2));
        float sum = 0.f;
#pragma unroll
        for (int i = 0; i < 16; ++i) { v[i] = __expf(v[i] - mx); sum += v[i]; }
        sum += __shfl_xor(sum, 1);
        sum += __shfl_xor(sum, 2);
        float inv = 1.0f / sum;
        us8 p0, p1;
#pragma unroll
        for (int i = 0; i < 8; ++i) {
            p0[i] = bf16_hi(v[i] * inv);
            p1[i] = bf16_hi(v[8 + i] * inv);
        }
        *(us8*)&Ps[srow * 72 + scb] = p0;       // Ps region disjoint from Ss region
        *(us8*)&Ps[srow * 72 + scb + 8] = p1;
    }
    __syncthreads();

    // ---- PV: O[64 q][128 d] = P[64][64] @ V; wave owns d cols wave*32..+32 ----
    f32x4 oa[4][2];
#pragma unroll
    for (int i = 0; i < 4; ++i)
#pragma unroll
        for (int j = 0; j < 2; ++j) { f32x4 z = {0.f, 0.f, 0.f, 0.f}; oa[i][j] = z; }
#pragma unroll
    for (int ks = 0; ks < 2; ++ks) {
        short8 bv0 = *(const short8*)&Vs[(wave * 32 + lm) * 72 + ks * 32 + quad * 8];
        short8 bv1 = *(const short8*)&Vs[(wave * 32 + 16 + lm) * 72 + ks * 32 + quad * 8];
#pragma unroll
        for (int i = 0; i < 4; ++i) {
            short8 af = *(const short8*)&Ps[(i * 16 + lm) * 72 + ks * 32 + quad * 8];
            oa[i][0] = __builtin_amdgcn_mfma_f32_16x16x32_bf16(af, bv0, oa[i][0], 0, 0, 0);
            oa[i][1] = __builtin_amdgcn_mfma_f32_16x16x32_bf16(af, bv1, oa[i][1], 0, 0, 0);
        }
    }
    __syncthreads();   // Ps/Vs reads done before Os overlays

#pragma unroll
    for (int i = 0; i < 4; ++i)
#pragma unroll
        for (int j = 0; j < 2; ++j)
#pragma unroll
            for (int r = 0; r < 4; ++r)
                Os[(i * 16 + quad * 4 + r) * 132 + wave * 32 + j * 16 + lm] = oa[i][j][r];
    __syncthreads();

    // ---- write bf16 O: thread -> (row = t>>2, 32 contiguous d) ----
    {
        int row = t >> 2, dstart = (t & 3) * 32;
        size_t obase = (rowbase + row) * C_DIM + h * HD + dstart;
#pragma unroll
        for (int c = 0; c < 4; ++c) {
            us8 hv;
#pragma unroll
            for (int i = 0; i < 8; ++i)
                hv[i] = bf16_hi(Os[row * 132 + dstart + c * 8 + i]);
            *(us8*)&Osp[obase + c * 8] = hv;
        }
    }
}

// ---------------- host ----------------
extern "C" void kernel_launch(void* const* d_in, const int* in_sizes, int n_in,
                              void* d_out, int out_size, void* d_ws, size_t ws_size,
                              hipStream_t stream) {
    const float* x  = (const float*)d_in[0];
    const float* Wq = (const float*)d_in[1];
    const float* bq = (const float*)d_in[2];
    const float* Wk = (const float*)d_in[3];
    const float* bk = (const float*)d_in[4];
    const float* Wv = (const float*)d_in[5];
    const float* bv = (const float*)d_in[6];
    const float* Wo = (const float*)d_in[7];
    const float* bo = (const float*)d_in[8];
    float* out = (float*)d_out;

    const size_t MB = 1024ull * 1024ull;
    char* base = (char*)d_ws;
    unsigned short* WspQ = (unsigned short*)(base + 0 * 2 * MB);
    unsigned short* WspK = (unsigned short*)(base + 1 * 2 * MB);
    unsigned short* WspV = (unsigned short*)(base + 2 * 2 * MB);
    unsigned short* WspO = (unsigned short*)(base + 3 * 2 * MB);

    // ws need = 16MiB (weights+pad) + BG*56MiB
    int BG = 8;
    while (BG > 1 && 16 * MB + (size_t)BG * 56 * MB > ws_size) BG >>= 1;

    char* p = base + 16 * MB;
    unsigned short* xsp = (unsigned short*)p;                 // [BG*L][C] bf16; aliased as Osp
    float* Qt = (float*)(p + (size_t)BG * 8 * MB);            // [BG*L][C] fp32
    float* Kt = (float*)(p + (size_t)BG * 24 * MB);           // [BG*L][C] fp32
    float* Vt = (float*)(p + (size_t)BG * 40 * MB);           // [BG][C][L] fp32 (V^T)

    dim3 tb(32, 8);
    split_w<<<dim3(32, 32), tb, 0, stream>>>(Wq, WspQ);
    split_w<<<dim3(32, 32), tb, 0, stream>>>(Wk, WspK);
    split_w<<<dim3(32, 32), tb, 0, stream>>>(Wv, WspV);
    split_w<<<dim3(32, 32), tb, 0, stream>>>(Wo, WspO);

    for (int b0 = 0; b0 < B_DIM; b0 += BG) {
        int M = BG * L_DIM;
        split_x<<<dim3(L_DIM / 64, C_DIM / 64, BG), 256, 0, stream>>>(x, xsp, b0);
        dim3 gg(C_DIM / TN, M / TM);
        gemm_bf16<<<gg, 256, 0, stream>>>(xsp, WspQ, bq, Qt, M, C_DIM, C_DIM, 0, 0);
        gemm_bf16<<<gg, 256, 0, stream>>>(xsp, WspK, bk, Kt, M, C_DIM, C_DIM, 0, 0);
        // V projection written TRANSPOSED (V^T [BG][C][L]) via the tmode=1 epilogue
        gemm_bf16<<<gg, 256, 0, stream>>>(xsp, WspV, bv, Vt, M, C_DIM, C_DIM, 1, 0);
        attn<<<BG * (L_DIM / CHUNK) * H_DIM, 256, 0, stream>>>(Qt, Kt, Vt, xsp);
        // O projection with fused transpose: writes out[b][c][l] directly
        gemm_bf16<<<gg, 256, 0, stream>>>(xsp, WspO, bo, out, M, C_DIM, C_DIM, 1, b0);
    }
}

// Round 5
// 696.908 us; speedup vs baseline: 2.0279x; 1.1497x over previous
//
#include <hip/hip_runtime.h>

// ---------------- types ----------------
typedef __attribute__((ext_vector_type(8))) short short8;
typedef __attribute__((ext_vector_type(8))) unsigned short us8;
typedef __attribute__((ext_vector_type(4))) float f32x4;

#define C_DIM 1024
#define L_DIM 4096
#define B_DIM 8
#define H_DIM 8
#define HD 128
#define CHUNK 64

// round-to-nearest-even fp32 -> bf16 (raw bits)
__device__ inline unsigned short bf16_hi(float f) {
    unsigned u = __float_as_uint(f);
    unsigned r = (u + 0x7FFFu + ((u >> 16) & 1u)) >> 16;
    return (unsigned short)r;
}

// ---------------- weight transpose+round: W[K][N] fp32 -> Wt[N][K] bf16 ----------------
__global__ void split_w(const float* __restrict__ W, unsigned short* __restrict__ Wt) {
    __shared__ float tile[32][33];
    int nb = blockIdx.x * 32;  // n base
    int kb = blockIdx.y * 32;  // k base
    for (int i = 0; i < 4; ++i)
        tile[threadIdx.y + i * 8][threadIdx.x] =
            W[(size_t)(kb + threadIdx.y + i * 8) * C_DIM + nb + threadIdx.x];
    __syncthreads();
    for (int i = 0; i < 4; ++i) {
        int n = nb + threadIdx.y + i * 8;
        int k = kb + threadIdx.x;
        float v = tile[threadIdx.x][threadIdx.y + i * 8]; // = W[k][n]
        Wt[(size_t)n * C_DIM + k] = bf16_hi(v);
    }
}

// ------------- x transpose+round: x[b][c][l] -> xsp[(b-b0)*L + l][C] bf16 -------------
__global__ __launch_bounds__(256) void split_x(const float* __restrict__ x,
                                               unsigned short* __restrict__ xsp, int b0) {
    __shared__ float tile[64][65];
    int t = threadIdx.x;
    int lb = blockIdx.x * 64, cb = blockIdx.y * 64, bp = blockIdx.z;
    const float* xp = x + ((size_t)(b0 + bp) * C_DIM + cb) * L_DIM + lb;
#pragma unroll
    for (int p = 0; p < 4; ++p) {
        int cr = p * 16 + (t >> 4);
        int lo4 = (t & 15) * 4;
        float4 v = *(const float4*)&xp[(size_t)cr * L_DIM + lo4];
        tile[lo4 + 0][cr] = v.x;
        tile[lo4 + 1][cr] = v.y;
        tile[lo4 + 2][cr] = v.z;
        tile[lo4 + 3][cr] = v.w;
    }
    __syncthreads();
#pragma unroll
    for (int p = 0; p < 2; ++p) {
        int l = p * 32 + (t >> 3);
        int c8 = (t & 7) * 8;
        us8 hv;
#pragma unroll
        for (int i = 0; i < 8; ++i)
            hv[i] = bf16_hi(tile[l][c8 + i]);
        size_t row = (size_t)bp * L_DIM + lb + l;
        *(us8*)&xsp[row * C_DIM + cb + c8] = hv;
    }
}

// ---------------- bf16 MFMA GEMM: Y = A[M][K] * Bt[N][K]^T + bias ----------------
// omode 0: fp32 [M][N]      omode 1: fp32 [b][N][L] (fused transpose, +b0)
// omode 2: bf16 [M][N]      omode 3: bf16 [b][N][L] (fused transpose)
#define TM 128
#define TN 128
#define BK 64
#define LDSS 72   // LDS row stride (bf16 elems): +8 pad -> 2-way-only aliasing

__global__ __launch_bounds__(256) void gemm_bf16(
    const unsigned short* __restrict__ A,   // [M][K] k-contig bf16 bits
    const unsigned short* __restrict__ Bt,  // [N][K] k-contig bf16 bits
    const float* __restrict__ bias,         // [N]
    void* __restrict__ Yv,
    int M, int N, int K, int omode, int b0)
{
    __shared__ unsigned short As[TM * LDSS];
    __shared__ unsigned short Bs[TN * LDSS];
    int t = threadIdx.x;

    // XCD-chunked swizzle (T1): consecutive hw blockIdx round-robin across 8 XCDs;
    // remap so each XCD gets a contiguous chunk -> blocks sharing an A panel are same-XCD.
    int nwg = gridDim.x * gridDim.y;
    int bid = blockIdx.y * gridDim.x + blockIdx.x;
    int bx, by;
    if ((nwg & 7) == 0) {
        int wg = (bid & 7) * (nwg >> 3) + (bid >> 3);
        bx = wg % gridDim.x; by = wg / gridDim.x;
    } else { bx = blockIdx.x; by = blockIdx.y; }

    int m0 = by * TM, n0 = bx * TN;
    int wave = t >> 6, lane = t & 63;
    int wr = wave >> 1, wc = wave & 1;
    int lm = lane & 15, quad = lane >> 4;

    f32x4 acc[4][4];
    for (int i = 0; i < 4; ++i)
        for (int j = 0; j < 4; ++j) { f32x4 z = {0.f, 0.f, 0.f, 0.f}; acc[i][j] = z; }

    const int lrow = t >> 3;        // 0..31
    const int lk = (t & 7) * 8;     // 0..56

    for (int kt = 0; kt < K; kt += BK) {
#pragma unroll
        for (int p = 0; p < 4; ++p) {
            int r = p * 32 + lrow;
            *(us8*)&As[r * LDSS + lk] = *(const us8*)&A[(size_t)(m0 + r) * K + kt + lk];
            *(us8*)&Bs[r * LDSS + lk] = *(const us8*)&Bt[(size_t)(n0 + r) * K + kt + lk];
        }
        __syncthreads();
#pragma unroll
        for (int s = 0; s < 2; ++s) {
            short8 af[4], bfr[4];
#pragma unroll
            for (int i = 0; i < 4; ++i)
                af[i] = *(const short8*)&As[(wr * 64 + i * 16 + lm) * LDSS + s * 32 + quad * 8];
#pragma unroll
            for (int j = 0; j < 4; ++j)
                bfr[j] = *(const short8*)&Bs[(wc * 64 + j * 16 + lm) * LDSS + s * 32 + quad * 8];
#pragma unroll
            for (int i = 0; i < 4; ++i)
#pragma unroll
                for (int j = 0; j < 4; ++j)
                    acc[i][j] = __builtin_amdgcn_mfma_f32_16x16x32_bf16(af[i], bfr[j], acc[i][j], 0, 0, 0);
        }
        __syncthreads();
    }

    // epilogue: C/D mapping col=lane&15, row=quad*4+reg  [verified m89/m91]
    if (omode == 0) {
        float* Y = (float*)Yv;
#pragma unroll
        for (int i = 0; i < 4; ++i) {
            int row = m0 + wr * 64 + i * 16 + quad * 4;
#pragma unroll
            for (int j = 0; j < 4; ++j) {
                int col = n0 + wc * 64 + j * 16 + lm;
                float b = bias[col];
#pragma unroll
                for (int r = 0; r < 4; ++r)
                    Y[(size_t)(row + r) * N + col] = acc[i][j][r] + b;
            }
        }
    } else if (omode == 2) {
        unsigned short* Y = (unsigned short*)Yv;
#pragma unroll
        for (int i = 0; i < 4; ++i) {
            int row = m0 + wr * 64 + i * 16 + quad * 4;
#pragma unroll
            for (int j = 0; j < 4; ++j) {
                int col = n0 + wc * 64 + j * 16 + lm;
                float b = bias[col];
#pragma unroll
                for (int r = 0; r < 4; ++r)
                    Y[(size_t)(row + r) * N + col] = bf16_hi(acc[i][j][r] + b);
            }
        }
    } else if (omode == 1) {
        float* Y = (float*)Yv;
#pragma unroll
        for (int i = 0; i < 4; ++i) {
            int row = m0 + wr * 64 + i * 16 + quad * 4;
            int bp = row >> 12;             // row / L_DIM
            int l = row & (L_DIM - 1);
#pragma unroll
            for (int j = 0; j < 4; ++j) {
                int col = n0 + wc * 64 + j * 16 + lm;
                float b = bias[col];
                float4 v;
                v.x = acc[i][j][0] + b; v.y = acc[i][j][1] + b;
                v.z = acc[i][j][2] + b; v.w = acc[i][j][3] + b;
                *(float4*)&Y[((size_t)(b0 + bp) * N + col) * L_DIM + l] = v;
            }
        }
    } else {  // omode 3: bf16 [b][N][L]
        unsigned short* Y = (unsigned short*)Yv;
#pragma unroll
        for (int i = 0; i < 4; ++i) {
            int row = m0 + wr * 64 + i * 16 + quad * 4;
            int bp = row >> 12;
            int l = row & (L_DIM - 1);
#pragma unroll
            for (int j = 0; j < 4; ++j) {
                int col = n0 + wc * 64 + j * 16 + lm;
                float b = bias[col];
                ushort4 v;
                v.x = bf16_hi(acc[i][j][0] + b); v.y = bf16_hi(acc[i][j][1] + b);
                v.z = bf16_hi(acc[i][j][2] + b); v.w = bf16_hi(acc[i][j][3] + b);
                *(ushort4*)&Y[((size_t)(b0 + bp) * N + col) * L_DIM + l] = v;
            }
        }
    }
}

// ---------------- attention (MFMA): one block per (b', chunk, head) ----------------
// Q,K bf16 [M][C]; V^T bf16 [BG][C][L]. Fragment mapping identical to gemm_bf16.
__global__ __launch_bounds__(256) void attn(
    const unsigned short* __restrict__ Qt, const unsigned short* __restrict__ Kt,
    const unsigned short* __restrict__ Vt,
    unsigned short* __restrict__ Osp)  // [BG*L][C] bf16
{
    __shared__ __align__(16) char smem[53248];
    unsigned short* Qs = (unsigned short*)smem;            // [64][136] bf16
    unsigned short* Ks = (unsigned short*)(smem + 17408);  // [64][136] bf16
    unsigned short* Vs = (unsigned short*)(smem + 34816);  // [128][72] bf16 (V^T: row=d, col=k)
    float* Ss = (float*)smem;                              // [64][68] fp32, overlays Qs
    unsigned short* Ps = (unsigned short*)(smem + 17408);  // [64][72] bf16, overlays Ks
    float* Os = (float*)smem;                              // [64][132] fp32, overlays Qs+Ks

    int t = threadIdx.x;
    int idx = blockIdx.x;
    int h = idx & 7;
    int chunk = (idx >> 3) & 63;
    int bp = idx >> 9;
    size_t rowbase = (size_t)bp * L_DIM + (size_t)chunk * CHUNK;
    const unsigned short* Qp = Qt + rowbase * C_DIM + h * HD;
    const unsigned short* Kp = Kt + rowbase * C_DIM + h * HD;
    const unsigned short* Vp = Vt + ((size_t)bp * C_DIM + h * HD) * L_DIM + (size_t)chunk * CHUNK;
    int wave = t >> 6, lane = t & 63;
    int lm = lane & 15, quad = lane >> 4;

    // ---- stage Q,K (64 rows x 128 c) and V^T (128 d-rows x 64 k): straight us8 copies ----
#pragma unroll
    for (int p = 0; p < 4; ++p) {
        int f = p * 256 + t;
        int row = f >> 4, c8 = (f & 15) * 8;
        *(us8*)&Qs[row * 136 + c8] = *(const us8*)&Qp[(size_t)row * C_DIM + c8];
        *(us8*)&Ks[row * 136 + c8] = *(const us8*)&Kp[(size_t)row * C_DIM + c8];
    }
#pragma unroll
    for (int p = 0; p < 4; ++p) {
        int f = p * 256 + t;
        int row = f >> 3, c8 = (f & 7) * 8;   // row = d 0..127, c8 = k
        *(us8*)&Vs[row * 72 + c8] = *(const us8*)&Vp[(size_t)row * L_DIM + c8];
    }
    __syncthreads();

    // ---- QK^T: S[64 q][64 k]; wave owns cols wave*16..+16 ----
    f32x4 sa[4];
#pragma unroll
    for (int i = 0; i < 4; ++i) { f32x4 z = {0.f, 0.f, 0.f, 0.f}; sa[i] = z; }
#pragma unroll
    for (int ks = 0; ks < 4; ++ks) {
        short8 bfr = *(const short8*)&Ks[(wave * 16 + lm) * 136 + ks * 32 + quad * 8];
#pragma unroll
        for (int i = 0; i < 4; ++i) {
            short8 af = *(const short8*)&Qs[(i * 16 + lm) * 136 + ks * 32 + quad * 8];
            sa[i] = __builtin_amdgcn_mfma_f32_16x16x32_bf16(af, bfr, sa[i], 0, 0, 0);
        }
    }
    __syncthreads();   // all QK^T LDS reads done before S overlays Qs

    const float scale = 0.08838834764831845f;  // 1/sqrt(128)
#pragma unroll
    for (int i = 0; i < 4; ++i)
#pragma unroll
        for (int r = 0; r < 4; ++r)
            Ss[(i * 16 + quad * 4 + r) * 68 + wave * 16 + lm] = sa[i][r] * scale;
    __syncthreads();

    // ---- softmax: 4 threads per row, 16 cols each, 4-lane shuffle reduce ----
    {
        int srow = t >> 2, scb = (t & 3) * 16;
        float v[16];
        float mx = -1e30f;
#pragma unroll
        for (int q = 0; q < 4; ++q) {
            float4 f = *(const float4*)&Ss[srow * 68 + scb + q * 4];
            v[q * 4 + 0] = f.x; v[q * 4 + 1] = f.y; v[q * 4 + 2] = f.z; v[q * 4 + 3] = f.w;
            mx = fmaxf(fmaxf(fmaxf(mx, f.x), fmaxf(f.y, f.z)), f.w);
        }
        mx = fmaxf(mx, __shfl_xor(mx, 1));
        mx = fmaxf(mx, __shfl_xor(mx, 2));
        float sum = 0.f;
#pragma unroll
        for (int i = 0; i < 16; ++i) { v[i] = __expf(v[i] - mx); sum += v[i]; }
        sum += __shfl_xor(sum, 1);
        sum += __shfl_xor(sum, 2);
        float inv = 1.0f / sum;
        us8 p0, p1;
#pragma unroll
        for (int i = 0; i < 8; ++i) {
            p0[i] = bf16_hi(v[i] * inv);
            p1[i] = bf16_hi(v[8 + i] * inv);
        }
        *(us8*)&Ps[srow * 72 + scb] = p0;       // Ps region disjoint from Ss region
        *(us8*)&Ps[srow * 72 + scb + 8] = p1;
    }
    __syncthreads();

    // ---- PV: O[64 q][128 d] = P[64][64] @ V; wave owns d cols wave*32..+32 ----
    f32x4 oa[4][2];
#pragma unroll
    for (int i = 0; i < 4; ++i)
#pragma unroll
        for (int j = 0; j < 2; ++j) { f32x4 z = {0.f, 0.f, 0.f, 0.f}; oa[i][j] = z; }
#pragma unroll
    for (int ks = 0; ks < 2; ++ks) {
        short8 bv0 = *(const short8*)&Vs[(wave * 32 + lm) * 72 + ks * 32 + quad * 8];
        short8 bv1 = *(const short8*)&Vs[(wave * 32 + 16 + lm) * 72 + ks * 32 + quad * 8];
#pragma unroll
        for (int i = 0; i < 4; ++i) {
            short8 af = *(const short8*)&Ps[(i * 16 + lm) * 72 + ks * 32 + quad * 8];
            oa[i][0] = __builtin_amdgcn_mfma_f32_16x16x32_bf16(af, bv0, oa[i][0], 0, 0, 0);
            oa[i][1] = __builtin_amdgcn_mfma_f32_16x16x32_bf16(af, bv1, oa[i][1], 0, 0, 0);
        }
    }
    __syncthreads();   // Ps/Vs reads done before Os overlays

#pragma unroll
    for (int i = 0; i < 4; ++i)
#pragma unroll
        for (int j = 0; j < 2; ++j)
#pragma unroll
            for (int r = 0; r < 4; ++r)
                Os[(i * 16 + quad * 4 + r) * 132 + wave * 32 + j * 16 + lm] = oa[i][j][r];
    __syncthreads();

    // ---- write bf16 O: thread -> (row = t>>2, 32 contiguous d) ----
    {
        int row = t >> 2, dstart = (t & 3) * 32;
        size_t obase = (rowbase + row) * C_DIM + h * HD + dstart;
#pragma unroll
        for (int c = 0; c < 4; ++c) {
            us8 hv;
#pragma unroll
            for (int i = 0; i < 8; ++i)
                hv[i] = bf16_hi(Os[row * 132 + dstart + c * 8 + i]);
            *(us8*)&Osp[obase + c * 8] = hv;
        }
    }
}

// ---------------- host ----------------
extern "C" void kernel_launch(void* const* d_in, const int* in_sizes, int n_in,
                              void* d_out, int out_size, void* d_ws, size_t ws_size,
                              hipStream_t stream) {
    const float* x  = (const float*)d_in[0];
    const float* Wq = (const float*)d_in[1];
    const float* bq = (const float*)d_in[2];
    const float* Wk = (const float*)d_in[3];
    const float* bk = (const float*)d_in[4];
    const float* Wv = (const float*)d_in[5];
    const float* bv = (const float*)d_in[6];
    const float* Wo = (const float*)d_in[7];
    const float* bo = (const float*)d_in[8];
    float* out = (float*)d_out;

    const size_t MB = 1024ull * 1024ull;
    char* base = (char*)d_ws;
    unsigned short* WspQ = (unsigned short*)(base + 0 * 2 * MB);
    unsigned short* WspK = (unsigned short*)(base + 1 * 2 * MB);
    unsigned short* WspV = (unsigned short*)(base + 2 * 2 * MB);
    unsigned short* WspO = (unsigned short*)(base + 3 * 2 * MB);

    // ws need = 16MiB (weights+pad) + BG*32MiB (xsp, Qb, Kb, Vb all bf16)
    int BG = 8;
    while (BG > 1 && 16 * MB + (size_t)BG * 32 * MB > ws_size) BG >>= 1;

    char* p = base + 16 * MB;
    unsigned short* xsp = (unsigned short*)p;                       // [BG*L][C] bf16; aliased as Osp
    unsigned short* Qtb = (unsigned short*)(p + (size_t)BG * 8 * MB);   // [BG*L][C] bf16
    unsigned short* Ktb = (unsigned short*)(p + (size_t)BG * 16 * MB);  // [BG*L][C] bf16
    unsigned short* Vtb = (unsigned short*)(p + (size_t)BG * 24 * MB);  // [BG][C][L] bf16 (V^T)

    dim3 tb(32, 8);
    split_w<<<dim3(32, 32), tb, 0, stream>>>(Wq, WspQ);
    split_w<<<dim3(32, 32), tb, 0, stream>>>(Wk, WspK);
    split_w<<<dim3(32, 32), tb, 0, stream>>>(Wv, WspV);
    split_w<<<dim3(32, 32), tb, 0, stream>>>(Wo, WspO);

    for (int b0 = 0; b0 < B_DIM; b0 += BG) {
        int M = BG * L_DIM;
        split_x<<<dim3(L_DIM / 64, C_DIM / 64, BG), 256, 0, stream>>>(x, xsp, b0);
        dim3 gg(C_DIM / TN, M / TM);
        gemm_bf16<<<gg, 256, 0, stream>>>(xsp, WspQ, bq, Qtb, M, C_DIM, C_DIM, 2, 0);
        gemm_bf16<<<gg, 256, 0, stream>>>(xsp, WspK, bk, Ktb, M, C_DIM, C_DIM, 2, 0);
        // V projection written TRANSPOSED bf16 (V^T [BG][C][L]) via omode 3
        gemm_bf16<<<gg, 256, 0, stream>>>(xsp, WspV, bv, Vtb, M, C_DIM, C_DIM, 3, 0);
        attn<<<BG * (L_DIM / CHUNK) * H_DIM, 256, 0, stream>>>(Qtb, Ktb, Vtb, xsp);
        // O projection with fused transpose: writes out[b][c][l] fp32 directly
        gemm_bf16<<<gg, 256, 0, stream>>>(xsp, WspO, bo, out, M, C_DIM, C_DIM, 1, b0);
    }
}